// Round 1
// baseline (891.302 us; speedup 1.0000x reference)
//
#include <hip/hip_runtime.h>

// Problem constants
constexpr int NB   = 2;      // batch
constexpr int ICH  = 64;     // input channels
constexpr int COUT = 640;    // qkv output channels (2*256 + 128)
constexpr int LDIM = 2744;   // 14^3 positions
constexpr int NHH  = 8;      // heads
constexpr int KSPLIT = 4;    // key-split for attention parallelism

// Workspace layout (float offsets)
constexpr int XPAD_OFF = 0;                         // 2*64*4096   = 524288
constexpr int Q_OFF    = 524288;                    // 2*256*2744  = 1404928
constexpr int KT_OFF   = Q_OFF + 1404928;           // 2*8*2744*32 = 1404928
constexpr int VT_OFF   = KT_OFF + 1404928;          // 2*8*2744*16 = 702464
constexpr int PART_OFF = VT_OFF + 702464;           // 2*8*2744*4*18 = 3161088
constexpr int OH_OFF   = PART_OFF + 3161088;        // 2*128*2744  = 702464
// total = 7,900,160 floats = 31.6 MB

// ---------------------------------------------------------------------------
// 1. Pad x (2,64,14,14,14) -> (2,64,16,16,16) with zero halo. Removes all
//    bounds checks from the conv inner loop.
__global__ __launch_bounds__(256) void pad_x_kernel(const float* __restrict__ x,
                                                    float* __restrict__ xpad) {
    int idx = blockIdx.x * 256 + threadIdx.x;     // over NB*ICH*4096
    if (idx >= NB * ICH * 4096) return;
    int c = idx >> 12;                            // n*64 + ic
    int r = idx & 4095;
    int z = r >> 8, y = (r >> 4) & 15, xx = r & 15;
    float v = 0.f;
    if (z >= 1 && z <= 14 && y >= 1 && y <= 14 && xx >= 1 && xx <= 14)
        v = x[c * LDIM + (z - 1) * 196 + (y - 1) * 14 + (xx - 1)];
    xpad[idx] = v;
}

// ---------------------------------------------------------------------------
// 2. Conv 3x3x3: block = (position-tile of 256, group of 8 out-channels, n).
//    Each thread: 8 accumulators; per tap 1 x-load amortized over 8 FMAs with
//    block-uniform weights (scalarized to s_load through the SMEM pipe).
//    Stores q in [n][c][p]; K and V transposed to [n][h][p][d] for the
//    attention kernel's uniform row loads.
__global__ __launch_bounds__(256) void conv_qkv_kernel(
        const float* __restrict__ xpad, const float* __restrict__ w,
        const float* __restrict__ b, float* __restrict__ qws,
        float* __restrict__ kT, float* __restrict__ vT) {
    const int pt = blockIdx.x, ocg = blockIdx.y, n = blockIdx.z;
    const int tid = threadIdx.x;
    const int p = pt * 256 + tid;
    const bool valid = p < LDIM;
    const int pc = valid ? p : LDIM - 1;
    const int z = pc / 196, r = pc % 196, y = r / 14, xx = r % 14;
    const int base0 = z * 256 + y * 16 + xx;   // padded coords: halo built in
    const float* xp = xpad + n * (ICH * 4096) + base0;
    const int oc0 = ocg * 8;
    const float* wb = w + oc0 * 1728;          // 1728 = 64*27 per out-channel

    float acc[8];
#pragma unroll
    for (int k = 0; k < 8; ++k) acc[k] = 0.f;

    for (int ic = 0; ic < ICH; ++ic) {
        const float* xb = xp + ic * 4096;
        const float* wc = wb + ic * 27;
#pragma unroll
        for (int t = 0; t < 27; ++t) {
            const int off = (t / 9) * 256 + ((t / 3) % 3) * 16 + (t % 3);
            const float xv = xb[off];
#pragma unroll
            for (int k = 0; k < 8; ++k)
                acc[k] = fmaf(wc[k * 1728 + t], xv, acc[k]);
        }
    }
    if (!valid) return;

#pragma unroll
    for (int k = 0; k < 8; ++k) {
        const int oc = oc0 + k;
        float val = acc[k] + b[oc];
        if (oc < 256) {                       // q, pre-scaled by 1/sqrt(32)
            qws[(n * 256 + oc) * LDIM + p] = val * 0.17677669529663687f;
        } else if (oc < 512) {                // k -> [n][h][p][32]
            const int c = oc - 256, h = c >> 5, d = c & 31;
            kT[((size_t)(n * NHH + h) * LDIM + p) * 32 + d] = val;
        } else {                              // v -> [n][h][p][16]
            const int c = oc - 512, h = c >> 4, d = c & 15;
            vT[((size_t)(n * NHH + h) * LDIM + p) * 16 + d] = val;
        }
    }
}

// ---------------------------------------------------------------------------
// 3. Flash-style attention partial: block = (q-tile of 256, key-split, n*h).
//    Thread = one query. Online softmax with rare rescale branch. K/V rows
//    are wave-uniform -> scalar loads.
__global__ __launch_bounds__(256) void attn_partial_kernel(
        const float* __restrict__ qws, const float* __restrict__ kT,
        const float* __restrict__ vT, float* __restrict__ part) {
    const int qt = blockIdx.x, ks = blockIdx.y, nh = blockIdx.z;
    const int n = nh >> 3, h = nh & 7;
    const int p = qt * 256 + threadIdx.x;
    const bool valid = p < LDIM;
    const int pc = valid ? p : LDIM - 1;

    float ql[32];
#pragma unroll
    for (int d = 0; d < 32; ++d)
        ql[d] = qws[(n * 256 + h * 32 + d) * LDIM + pc];

    const float* kh = kT + (size_t)nh * LDIM * 32;
    const float* vh = vT + (size_t)nh * LDIM * 16;
    const int j0 = ks * (LDIM / KSPLIT);
    const int j1 = j0 + (LDIM / KSPLIT);

    float m = -1e30f, s = 0.f;
    float o[16];
#pragma unroll
    for (int d = 0; d < 16; ++d) o[d] = 0.f;

    for (int j = j0; j < j1; ++j) {
        const float* kj = kh + (size_t)j * 32;   // wave-uniform -> s_load
        float l0 = 0.f, l1 = 0.f, l2 = 0.f, l3 = 0.f;
#pragma unroll
        for (int d = 0; d < 32; d += 4) {
            l0 = fmaf(ql[d + 0], kj[d + 0], l0);
            l1 = fmaf(ql[d + 1], kj[d + 1], l1);
            l2 = fmaf(ql[d + 2], kj[d + 2], l2);
            l3 = fmaf(ql[d + 3], kj[d + 3], l3);
        }
        const float logit = (l0 + l1) + (l2 + l3);
        const float* vj = vh + (size_t)j * 16;   // wave-uniform -> s_load
        if (logit > m) {                         // rare rescale
            const float corr = __expf(m - logit);
            m = logit;
            s *= corr;
#pragma unroll
            for (int d = 0; d < 16; ++d) o[d] *= corr;
        }
        const float e = __expf(logit - m);
        s += e;
#pragma unroll
        for (int d = 0; d < 16; ++d) o[d] = fmaf(e, vj[d], o[d]);
    }
    if (!valid) return;
    float* pp = part + ((size_t)(nh * LDIM + p) * KSPLIT + ks) * 18;
    pp[0] = m;
    pp[1] = s;
#pragma unroll
    for (int d = 0; d < 16; ++d) pp[2 + d] = o[d];
}

// ---------------------------------------------------------------------------
// 4. Combine key-split partials; write Oh in [n][c][p] (c = h*16+dv).
__global__ __launch_bounds__(256) void attn_combine_kernel(
        const float* __restrict__ part, float* __restrict__ Oh) {
    const int idx = blockIdx.x * 256 + threadIdx.x;   // over NB*NHH*LDIM
    if (idx >= NB * NHH * LDIM) return;
    const int nh = idx / LDIM, p = idx % LDIM;
    const int n = nh >> 3, h = nh & 7;
    const float* pp = part + (size_t)idx * (KSPLIT * 18);
    float M = -1e30f;
#pragma unroll
    for (int ks = 0; ks < KSPLIT; ++ks) M = fmaxf(M, pp[ks * 18]);
    float S = 0.f;
    float o[16];
#pragma unroll
    for (int d = 0; d < 16; ++d) o[d] = 0.f;
#pragma unroll
    for (int ks = 0; ks < KSPLIT; ++ks) {
        const float e = __expf(pp[ks * 18] - M);
        S = fmaf(pp[ks * 18 + 1], e, S);
#pragma unroll
        for (int d = 0; d < 16; ++d) o[d] = fmaf(pp[ks * 18 + 2 + d], e, o[d]);
    }
    const float inv = 1.f / S;
#pragma unroll
    for (int d = 0; d < 16; ++d)
        Oh[(size_t)(n * 128 + h * 16 + d) * LDIM + p] = o[d] * inv;
}

// ---------------------------------------------------------------------------
// 5. Output projection: out[n][o][p] = sum_i W[o][i]*Oh[n][i][p] + b[o].
//    Block = (p-tile, group of 16 out-channels, n); weights uniform -> s_load.
__global__ __launch_bounds__(256) void out_proj_kernel(
        const float* __restrict__ Oh, const float* __restrict__ ow,
        const float* __restrict__ ob, float* __restrict__ out) {
    const int pt = blockIdx.x, og = blockIdx.y, n = blockIdx.z;
    const int p = pt * 256 + threadIdx.x;
    const bool valid = p < LDIM;
    const int pc = valid ? p : LDIM - 1;
    float acc[16];
#pragma unroll
    for (int k = 0; k < 16; ++k) acc[k] = 0.f;
    const float* ohp = Oh + (size_t)n * 128 * LDIM + pc;
    const int o0 = og * 16;
    for (int i = 0; i < 128; ++i) {
        const float v = ohp[(size_t)i * LDIM];
#pragma unroll
        for (int k = 0; k < 16; ++k)
            acc[k] = fmaf(ow[(o0 + k) * 128 + i], v, acc[k]);
    }
    if (!valid) return;
#pragma unroll
    for (int k = 0; k < 16; ++k)
        out[(size_t)(n * 128 + o0 + k) * LDIM + p] = acc[k] + ob[o0 + k];
}

// ---------------------------------------------------------------------------
extern "C" void kernel_launch(void* const* d_in, const int* in_sizes, int n_in,
                              void* d_out, int out_size, void* d_ws, size_t ws_size,
                              hipStream_t stream) {
    const float* x     = (const float*)d_in[0];
    const float* qkv_w = (const float*)d_in[1];
    const float* qkv_b = (const float*)d_in[2];
    const float* out_w = (const float*)d_in[3];
    const float* out_b = (const float*)d_in[4];
    float* ws   = (float*)d_ws;
    float* xpad = ws + XPAD_OFF;
    float* qws  = ws + Q_OFF;
    float* kT   = ws + KT_OFF;
    float* vT   = ws + VT_OFF;
    float* part = ws + PART_OFF;
    float* Oh   = ws + OH_OFF;
    float* out  = (float*)d_out;

    pad_x_kernel<<<(NB * ICH * 4096) / 256, 256, 0, stream>>>(x, xpad);
    conv_qkv_kernel<<<dim3(11, COUT / 8, NB), 256, 0, stream>>>(xpad, qkv_w, qkv_b,
                                                                qws, kT, vT);
    attn_partial_kernel<<<dim3(11, KSPLIT, NB * NHH), 256, 0, stream>>>(qws, kT, vT,
                                                                        part);
    attn_combine_kernel<<<(NB * NHH * LDIM + 255) / 256, 256, 0, stream>>>(part, Oh);
    out_proj_kernel<<<dim3(11, 8, NB), 256, 0, stream>>>(Oh, out_w, out_b, out);
}

// Round 2
// 478.401 us; speedup vs baseline: 1.8631x; 1.8631x over previous
//
#include <hip/hip_runtime.h>

typedef short bf16x8 __attribute__((ext_vector_type(8)));
typedef float f32x4 __attribute__((ext_vector_type(4)));
typedef unsigned short ushort_t;

// Problem constants
constexpr int NB   = 2;      // batch
constexpr int ICH  = 64;     // input channels
constexpr int COUT = 640;    // qkv output channels (2*256 + 128)
constexpr int LDIM = 2744;   // 14^3 positions
constexpr int LPAD = 2752;   // padded to multiple of 32 keys
constexpr int NHH  = 8;      // heads

// Workspace layout (float offsets)
constexpr size_t XPAD_OFF = 0;                      // 2*64*4096 = 524288 f
constexpr size_t Q_OFF    = 524288;                 // qT bf16: 2*8*2752*32 = 1409024 -> 704512 f
constexpr size_t K_OFF    = Q_OFF + 704512;         // kT bf16: same
constexpr size_t V_OFF    = K_OFF + 704512;         // vTT bf16: 2*8*16*2752 = 704512 -> 352256 f
constexpr size_t OH_OFF   = V_OFF + 352256;         // Oh fp32: 2*128*2744 = 702464 f
// total ~ 2.99M floats = 12 MB

// fp32 -> bf16 round-to-nearest-even (inputs guaranteed finite)
__device__ __forceinline__ ushort_t bf16_rn(float x) {
    unsigned u = __float_as_uint(x);
    u += 0x7FFFu + ((u >> 16) & 1u);
    return (ushort_t)(u >> 16);
}
__device__ __forceinline__ unsigned pack2(float a, float b) {
    return (unsigned)bf16_rn(a) | ((unsigned)bf16_rn(b) << 16);
}

// ---------------------------------------------------------------------------
// 1. Pad x (2,64,14,14,14) -> (2,64,16,16,16) with zero halo.
__global__ __launch_bounds__(256) void pad_x_kernel(const float* __restrict__ x,
                                                    float* __restrict__ xpad) {
    int idx = blockIdx.x * 256 + threadIdx.x;
    if (idx >= NB * ICH * 4096) return;
    int c = idx >> 12;
    int r = idx & 4095;
    int z = r >> 8, y = (r >> 4) & 15, xx = r & 15;
    float v = 0.f;
    if (z >= 1 && z <= 14 && y >= 1 && y <= 14 && xx >= 1 && xx <= 14)
        v = x[c * LDIM + (z - 1) * 196 + (y - 1) * 14 + (xx - 1)];
    xpad[idx] = v;
}

// ---------------------------------------------------------------------------
// 2. Conv 3x3x3. Epilogue writes bf16 Q,K in [nh][p][32] (MFMA-fragment
//    friendly: 16B contiguous per (row, 8-d slice)) and V transposed to
//    [nh][dv][p] for contiguous B-operand... (A-operand of O^T) loads.
__global__ __launch_bounds__(256) void conv_qkv_kernel(
        const float* __restrict__ xpad, const float* __restrict__ w,
        const float* __restrict__ b, ushort_t* __restrict__ qT,
        ushort_t* __restrict__ kT, ushort_t* __restrict__ vTT) {
    const int pt = blockIdx.x, ocg = blockIdx.y, n = blockIdx.z;
    const int tid = threadIdx.x;
    const int p = pt * 256 + tid;
    const bool valid = p < LDIM;
    const int pc = valid ? p : LDIM - 1;
    const int z = pc / 196, r = pc % 196, y = r / 14, xx = r % 14;
    const int base0 = z * 256 + y * 16 + xx;
    const float* xp = xpad + n * (ICH * 4096) + base0;
    const int oc0 = ocg * 8;
    const float* wb = w + oc0 * 1728;

    float acc[8];
#pragma unroll
    for (int k = 0; k < 8; ++k) acc[k] = 0.f;

    for (int ic = 0; ic < ICH; ++ic) {
        const float* xb = xp + ic * 4096;
        const float* wc = wb + ic * 27;
#pragma unroll
        for (int t = 0; t < 27; ++t) {
            const int off = (t / 9) * 256 + ((t / 3) % 3) * 16 + (t % 3);
            const float xv = xb[off];
#pragma unroll
            for (int k = 0; k < 8; ++k)
                acc[k] = fmaf(wc[k * 1728 + t], xv, acc[k]);
        }
    }
    if (!valid) return;

#pragma unroll
    for (int k = 0; k < 8; ++k) {
        const int oc = oc0 + k;
        float val = acc[k] + b[oc];
        if (oc < 256) {                       // q, pre-scaled by 1/sqrt(32)
            const int h = oc >> 5, d = oc & 31;
            qT[((size_t)(n * NHH + h) * LPAD + p) * 32 + d] =
                bf16_rn(val * 0.17677669529663687f);
        } else if (oc < 512) {                // k -> [nh][p][32]
            const int c = oc - 256, h = c >> 5, d = c & 31;
            kT[((size_t)(n * NHH + h) * LPAD + p) * 32 + d] = bf16_rn(val);
        } else {                              // v -> [nh][dv][p]
            const int c = oc - 512, h = c >> 4, d = c & 15;
            vTT[((size_t)(n * NHH + h) * 16 + d) * LPAD + p] = bf16_rn(val);
        }
    }
}

// ---------------------------------------------------------------------------
// 3. Flash attention with bf16 MFMA 16x16x32.
//    Block = 4 waves, each wave owns 16 queries; full key sweep (no split).
//    St = mfma(A=Kfrag, B=Qfrag): St[key][q], key=(lane>>4)*4+reg, q=lane&15.
//    Softmax state (m,s) is lane-local for query lane&15 (replicated x4).
//    O^T = mfma(A=V^T frag, B=Pfrag, C=O): O[dv][q], q=lane&15 -> rescale is
//    shuffle-free. P needs an 8-shuffle cross-group key redistribution.
__global__ __launch_bounds__(256) void attn_mfma_kernel(
        const ushort_t* __restrict__ qT, const ushort_t* __restrict__ kT,
        const ushort_t* __restrict__ vTT, float* __restrict__ Oh) {
    const int nh = blockIdx.y, n = nh >> 3, h = nh & 7;
    const int wave = threadIdx.x >> 6, lane = threadIdx.x & 63;
    const int lq = lane & 15, g = lane >> 4;
    const int q0 = blockIdx.x * 64 + wave * 16;

    const bf16x8 qf = *reinterpret_cast<const bf16x8*>(
        qT + ((size_t)nh * LPAD + q0 + lq) * 32 + g * 8);
    const ushort_t* kbase = kT + (size_t)nh * LPAD * 32;
    const ushort_t* vbase = vTT + ((size_t)nh * 16 + lq) * LPAD;

    f32x4 o = {0.f, 0.f, 0.f, 0.f};
    float m = -1e30f, s = 0.f;
    const int srcA = lq + 32 * (g & 1);   // source lane for key-halves
    const int srcB = srcA + 16;

    for (int kb = 0; kb < LDIM; kb += 32) {
        const bf16x8 kA = *reinterpret_cast<const bf16x8*>(
            kbase + (size_t)(kb + lq) * 32 + g * 8);
        const bf16x8 kB = *reinterpret_cast<const bf16x8*>(
            kbase + (size_t)(kb + 16 + lq) * 32 + g * 8);
        const bf16x8 vf = *reinterpret_cast<const bf16x8*>(vbase + kb + g * 8);

        const f32x4 z = {0.f, 0.f, 0.f, 0.f};
        f32x4 st0 = __builtin_amdgcn_mfma_f32_16x16x32_bf16(kA, qf, z, 0, 0, 0);
        f32x4 st1 = __builtin_amdgcn_mfma_f32_16x16x32_bf16(kB, qf, z, 0, 0, 0);

        float p0 = st0[0], p1 = st0[1], p2 = st0[2], p3 = st0[3];
        float p4 = st1[0], p5 = st1[1], p6 = st1[2], p7 = st1[3];

        float lmax = fmaxf(fmaxf(fmaxf(p0, p1), fmaxf(p2, p3)),
                           fmaxf(fmaxf(p4, p5), fmaxf(p6, p7)));
        lmax = fmaxf(lmax, __shfl_xor(lmax, 16));
        lmax = fmaxf(lmax, __shfl_xor(lmax, 32));
        const float mnew = fmaxf(m, lmax);
        const float corr = __expf(m - mnew);
        m = mnew;

        p0 = __expf(p0 - m); p1 = __expf(p1 - m);
        p2 = __expf(p2 - m); p3 = __expf(p3 - m);
        p4 = __expf(p4 - m); p5 = __expf(p5 - m);
        p6 = __expf(p6 - m); p7 = __expf(p7 - m);

        if (kb + 32 > LDIM) {                 // mask tail keys (>=2744)
            if (kb + 4 * g + 0  >= LDIM) p0 = 0.f;
            if (kb + 4 * g + 1  >= LDIM) p1 = 0.f;
            if (kb + 4 * g + 2  >= LDIM) p2 = 0.f;
            if (kb + 4 * g + 3  >= LDIM) p3 = 0.f;
            if (kb + 16 + 4 * g + 0 >= LDIM) p4 = 0.f;
            if (kb + 16 + 4 * g + 1 >= LDIM) p5 = 0.f;
            if (kb + 16 + 4 * g + 2 >= LDIM) p6 = 0.f;
            if (kb + 16 + 4 * g + 3 >= LDIM) p7 = 0.f;
        }

        float ls = ((p0 + p1) + (p2 + p3)) + ((p4 + p5) + (p6 + p7));
        ls += __shfl_xor(ls, 16);
        ls += __shfl_xor(ls, 32);
        s = s * corr + ls;
        o[0] *= corr; o[1] *= corr; o[2] *= corr; o[3] *= corr;

        // P^T (keys at 4g+r per group) -> B-operand layout (keys 8g'+j)
        const unsigned b0 = pack2(p0, p1), b1 = pack2(p2, p3);
        const unsigned b2 = pack2(p4, p5), b3 = pack2(p6, p7);
        const unsigned x0 = __shfl((int)b0, srcA), x1 = __shfl((int)b1, srcA);
        const unsigned x2 = __shfl((int)b0, srcB), x3 = __shfl((int)b1, srcB);
        const unsigned y0 = __shfl((int)b2, srcA), y1 = __shfl((int)b3, srcA);
        const unsigned y2 = __shfl((int)b2, srcB), y3 = __shfl((int)b3, srcB);
        const bool lo = g < 2;
        union { unsigned u[4]; bf16x8 v; } pw;
        pw.u[0] = lo ? x0 : y0;
        pw.u[1] = lo ? x1 : y1;
        pw.u[2] = lo ? x2 : y2;
        pw.u[3] = lo ? x3 : y3;

        o = __builtin_amdgcn_mfma_f32_16x16x32_bf16(vf, pw.v, o, 0, 0, 0);
    }

    const int q = q0 + lq;
    if (q < LDIM) {
        const float inv = 1.f / s;
#pragma unroll
        for (int r = 0; r < 4; ++r)
            Oh[((size_t)(n * 128 + h * 16 + g * 4 + r)) * LDIM + q] = o[r] * inv;
    }
}

// ---------------------------------------------------------------------------
// 4. Output projection (fp32): out[n][o][p] = sum_i W[o][i]*Oh[n][i][p] + b[o].
__global__ __launch_bounds__(256) void out_proj_kernel(
        const float* __restrict__ Oh, const float* __restrict__ ow,
        const float* __restrict__ ob, float* __restrict__ out) {
    const int pt = blockIdx.x, og = blockIdx.y, n = blockIdx.z;
    const int p = pt * 256 + threadIdx.x;
    const bool valid = p < LDIM;
    const int pc = valid ? p : LDIM - 1;
    float acc[16];
#pragma unroll
    for (int k = 0; k < 16; ++k) acc[k] = 0.f;
    const float* ohp = Oh + (size_t)n * 128 * LDIM + pc;
    const int o0 = og * 16;
    for (int i = 0; i < 128; ++i) {
        const float v = ohp[(size_t)i * LDIM];
#pragma unroll
        for (int k = 0; k < 16; ++k)
            acc[k] = fmaf(ow[(o0 + k) * 128 + i], v, acc[k]);
    }
    if (!valid) return;
#pragma unroll
    for (int k = 0; k < 16; ++k)
        out[(size_t)(n * 128 + o0 + k) * LDIM + p] = acc[k] + ob[o0 + k];
}

// ---------------------------------------------------------------------------
extern "C" void kernel_launch(void* const* d_in, const int* in_sizes, int n_in,
                              void* d_out, int out_size, void* d_ws, size_t ws_size,
                              hipStream_t stream) {
    const float* x     = (const float*)d_in[0];
    const float* qkv_w = (const float*)d_in[1];
    const float* qkv_b = (const float*)d_in[2];
    const float* out_w = (const float*)d_in[3];
    const float* out_b = (const float*)d_in[4];
    float* ws   = (float*)d_ws;
    float*    xpad = ws + XPAD_OFF;
    ushort_t* qT   = (ushort_t*)(ws + Q_OFF);
    ushort_t* kT   = (ushort_t*)(ws + K_OFF);
    ushort_t* vTT  = (ushort_t*)(ws + V_OFF);
    float*    Oh   = ws + OH_OFF;
    float*    out  = (float*)d_out;

    pad_x_kernel<<<(NB * ICH * 4096) / 256, 256, 0, stream>>>(x, xpad);
    conv_qkv_kernel<<<dim3(11, COUT / 8, NB), 256, 0, stream>>>(xpad, qkv_w, qkv_b,
                                                                qT, kT, vTT);
    attn_mfma_kernel<<<dim3(43, NB * NHH), 256, 0, stream>>>(qT, kT, vTT, Oh);
    out_proj_kernel<<<dim3(11, 8, NB), 256, 0, stream>>>(Oh, out_w, out_b, out);
}

// Round 3
// 285.260 us; speedup vs baseline: 3.1245x; 1.6771x over previous
//
#include <hip/hip_runtime.h>

typedef short bf16x8 __attribute__((ext_vector_type(8)));
typedef float f32x4 __attribute__((ext_vector_type(4)));
typedef unsigned short ushort_t;

// Problem constants
constexpr int NB   = 2;      // batch
constexpr int ICH  = 64;     // input channels
constexpr int LDIM = 2744;   // 14^3 positions
constexpr int LPAD = 2752;   // padded to multiple of 32 keys
constexpr int NHH  = 8;      // heads

// Workspace layout (float offsets)
// xpadT2: [n][4096 padded pos][128 ushort: xh(64), xl(64)]  -> 2*4096*128 us = 524288 f
// wT2   : [t 27][oc 640][128 ushort: wh(64), wl(64)]        -> 27*640*128 us = 1105920 f
// qT    : bf16 [nh 16][p 2752][32]                          -> 704512 f
// kT    : bf16 [nh 16][p 2752][32]                          -> 704512 f
// vTT   : bf16 [nh 16][dv 16][p 2752]                       -> 352256 f
// Oh    : fp32 [n 2][128][2744]                             -> 702464 f
constexpr size_t XPT_OFF = 0;
constexpr size_t WT_OFF  = 524288;
constexpr size_t Q_OFF   = WT_OFF + 1105920;
constexpr size_t K_OFF   = Q_OFF + 704512;
constexpr size_t V_OFF   = K_OFF + 704512;
constexpr size_t OH_OFF  = V_OFF + 352256;
// total = 4,093,952 floats = 16.4 MB

// fp32 -> bf16 round-to-nearest-even (inputs guaranteed finite)
__device__ __forceinline__ ushort_t bf16_rn(float x) {
    unsigned u = __float_as_uint(x);
    u += 0x7FFFu + ((u >> 16) & 1u);
    return (ushort_t)(u >> 16);
}
__device__ __forceinline__ float bf16_f(ushort_t h) {
    return __uint_as_float((unsigned)h << 16);
}
__device__ __forceinline__ unsigned pack2(float a, float b) {
    return (unsigned)bf16_rn(a) | ((unsigned)bf16_rn(b) << 16);
}

// ---------------------------------------------------------------------------
// 1. Pad + transpose + bf16-split x: (2,64,14^3) -> [n][pos 16^3][xh 64 | xl 64]
__global__ __launch_bounds__(256) void pad_split_x_kernel(
        const float* __restrict__ x, ushort_t* __restrict__ xpT) {
    int idx = blockIdx.x * 256 + threadIdx.x;      // over 2*4096*64
    int n = idx >> 18;
    int r = idx & 0x3FFFF;
    int pos = r >> 6, ic = r & 63;
    int z = pos >> 8, y = (pos >> 4) & 15, xx = pos & 15;
    float v = 0.f;
    if (z >= 1 && z <= 14 && y >= 1 && y <= 14 && xx >= 1 && xx <= 14)
        v = x[(n * 64 + ic) * LDIM + (z - 1) * 196 + (y - 1) * 14 + (xx - 1)];
    ushort_t hi = bf16_rn(v);
    float lo = v - bf16_f(hi);
    ushort_t* row = xpT + (size_t)(n * 4096 + pos) * 128;
    row[ic] = hi;
    row[64 + ic] = bf16_rn(lo);
}

// ---------------------------------------------------------------------------
// 2. Transpose + bf16-split weights: [oc 640][ic 64][t 27] -> [t][oc][wh 64 | wl 64]
__global__ __launch_bounds__(256) void w_split_kernel(
        const float* __restrict__ w, ushort_t* __restrict__ wT) {
    int idx = blockIdx.x * 256 + threadIdx.x;      // over 27*640*64
    int t = idx / 40960;
    int r = idx % 40960;
    int oc = r >> 6, ic = r & 63;
    float v = w[(oc * 64 + ic) * 27 + t];
    ushort_t hi = bf16_rn(v);
    float lo = v - bf16_f(hi);
    ushort_t* row = wT + (size_t)(t * 640 + oc) * 128;
    row[ic] = hi;
    row[64 + ic] = bf16_rn(lo);
}

// ---------------------------------------------------------------------------
// 3. Conv 3x3x3 as 27 shifted K=64 MFMA GEMM-accumulates, 3-pass bf16 split
//    (Wh·Xh + Wl·Xh + Wh·Xl => fp32-accurate). Block = 4 waves; block tile
//    64 oc x 256 p; wave tile 64 oc x 64 p (acc = 4x4 f32x4).
//    A-frag: lane holds W[oc0+lq][g*8+j]; B-frag: lane holds X[pos(p)][g*8+j];
//    C: col(p)=lane&15, row(oc)=g*4+i.
__global__ __launch_bounds__(256) void conv_mfma_kernel(
        const ushort_t* __restrict__ xpT, const ushort_t* __restrict__ wT,
        const float* __restrict__ b, ushort_t* __restrict__ qT,
        ushort_t* __restrict__ kT, ushort_t* __restrict__ vTT) {
    const int n = blockIdx.z, ocg = blockIdx.y;
    const int wave = threadIdx.x >> 6, lane = threadIdx.x & 63;
    const int lq = lane & 15, g = lane >> 4;
    const int p0 = blockIdx.x * 256 + wave * 64;
    const int oc0 = ocg * 64;

    // per-psub B column byte offsets into xpadT2
    unsigned boff[4];
    int pcol[4];
#pragma unroll
    for (int ps = 0; ps < 4; ++ps) {
        int p = p0 + ps * 16 + lq;
        pcol[ps] = p;
        int pc = p < LDIM ? p : LDIM - 1;
        int z = pc / 196, rr = pc % 196, y = rr / 14, xx = rr % 14;
        boff[ps] = (unsigned)(n * 4096 + z * 256 + y * 16 + xx) * 256u + g * 16u;
    }
    const unsigned aoff = (unsigned)(oc0 + lq) * 256u + (unsigned)g * 16u;

    f32x4 acc[4][4];
#pragma unroll
    for (int os = 0; os < 4; ++os)
#pragma unroll
        for (int ps = 0; ps < 4; ++ps)
            acc[os][ps] = (f32x4){0.f, 0.f, 0.f, 0.f};

    const char* xb = (const char*)xpT;
    const char* wb = (const char*)wT;

    for (int t = 0; t < 27; ++t) {
        const int tz = t / 9, tr = t % 9, ty = tr / 3, tx = tr % 3;
        const unsigned toff = (unsigned)(tz * 256 + ty * 16 + tx) * 256u;
        const char* wrow = wb + (size_t)t * 163840u + aoff;

        bf16x8 bhf[4][2], blf[4][2];
#pragma unroll
        for (int ps = 0; ps < 4; ++ps) {
            const char* bp = xb + boff[ps] + toff;
            bhf[ps][0] = *(const bf16x8*)(bp);
            bhf[ps][1] = *(const bf16x8*)(bp + 64);
            blf[ps][0] = *(const bf16x8*)(bp + 128);
            blf[ps][1] = *(const bf16x8*)(bp + 192);
        }
#pragma unroll
        for (int os = 0; os < 4; ++os) {
            const char* ap = wrow + os * 4096;
            const bf16x8 ah0 = *(const bf16x8*)(ap);
            const bf16x8 ah1 = *(const bf16x8*)(ap + 64);
            const bf16x8 al0 = *(const bf16x8*)(ap + 128);
            const bf16x8 al1 = *(const bf16x8*)(ap + 192);
#pragma unroll
            for (int ps = 0; ps < 4; ++ps) {
                f32x4 a = acc[os][ps];
                a = __builtin_amdgcn_mfma_f32_16x16x32_bf16(ah0, bhf[ps][0], a, 0, 0, 0);
                a = __builtin_amdgcn_mfma_f32_16x16x32_bf16(ah1, bhf[ps][1], a, 0, 0, 0);
                a = __builtin_amdgcn_mfma_f32_16x16x32_bf16(al0, bhf[ps][0], a, 0, 0, 0);
                a = __builtin_amdgcn_mfma_f32_16x16x32_bf16(al1, bhf[ps][1], a, 0, 0, 0);
                a = __builtin_amdgcn_mfma_f32_16x16x32_bf16(ah0, blf[ps][0], a, 0, 0, 0);
                a = __builtin_amdgcn_mfma_f32_16x16x32_bf16(ah1, blf[ps][1], a, 0, 0, 0);
                acc[os][ps] = a;
            }
        }
    }

    // Epilogue: bias + route to q/k/v (branch is block-uniform: ocg 0-3 q,
    // 4-7 k, 8-9 v).
#pragma unroll
    for (int os = 0; os < 4; ++os) {
        float bias[4];
#pragma unroll
        for (int i = 0; i < 4; ++i) bias[i] = b[oc0 + os * 16 + g * 4 + i];
#pragma unroll
        for (int ps = 0; ps < 4; ++ps) {
            if (pcol[ps] >= LDIM) continue;
            const int p = pcol[ps];
#pragma unroll
            for (int i = 0; i < 4; ++i) {
                const int oc = oc0 + os * 16 + g * 4 + i;
                const float val = acc[os][ps][i] + bias[i];
                if (oc0 < 256) {
                    const int h = oc >> 5, d = oc & 31;
                    qT[((size_t)(n * NHH + h) * LPAD + p) * 32 + d] =
                        bf16_rn(val * 0.17677669529663687f);
                } else if (oc0 < 512) {
                    const int c = oc - 256, h = c >> 5, d = c & 31;
                    kT[((size_t)(n * NHH + h) * LPAD + p) * 32 + d] = bf16_rn(val);
                } else {
                    const int c = oc - 512, h = c >> 4, d = c & 15;
                    vTT[((size_t)(n * NHH + h) * 16 + d) * LPAD + p] = bf16_rn(val);
                }
            }
        }
    }
}

// ---------------------------------------------------------------------------
// 4. Flash attention with bf16 MFMA 16x16x32 (unchanged from round 2).
__global__ __launch_bounds__(256) void attn_mfma_kernel(
        const ushort_t* __restrict__ qT, const ushort_t* __restrict__ kT,
        const ushort_t* __restrict__ vTT, float* __restrict__ Oh) {
    const int nh = blockIdx.y, n = nh >> 3, h = nh & 7;
    const int wave = threadIdx.x >> 6, lane = threadIdx.x & 63;
    const int lq = lane & 15, g = lane >> 4;
    const int q0 = blockIdx.x * 64 + wave * 16;

    const bf16x8 qf = *reinterpret_cast<const bf16x8*>(
        qT + ((size_t)nh * LPAD + q0 + lq) * 32 + g * 8);
    const ushort_t* kbase = kT + (size_t)nh * LPAD * 32;
    const ushort_t* vbase = vTT + ((size_t)nh * 16 + lq) * LPAD;

    f32x4 o = {0.f, 0.f, 0.f, 0.f};
    float m = -1e30f, s = 0.f;
    const int srcA = lq + 32 * (g & 1);
    const int srcB = srcA + 16;

    for (int kb = 0; kb < LDIM; kb += 32) {
        const bf16x8 kA = *reinterpret_cast<const bf16x8*>(
            kbase + (size_t)(kb + lq) * 32 + g * 8);
        const bf16x8 kB = *reinterpret_cast<const bf16x8*>(
            kbase + (size_t)(kb + 16 + lq) * 32 + g * 8);
        const bf16x8 vf = *reinterpret_cast<const bf16x8*>(vbase + kb + g * 8);

        const f32x4 z = {0.f, 0.f, 0.f, 0.f};
        f32x4 st0 = __builtin_amdgcn_mfma_f32_16x16x32_bf16(kA, qf, z, 0, 0, 0);
        f32x4 st1 = __builtin_amdgcn_mfma_f32_16x16x32_bf16(kB, qf, z, 0, 0, 0);

        float p0 = st0[0], p1 = st0[1], p2 = st0[2], p3 = st0[3];
        float p4 = st1[0], p5 = st1[1], p6 = st1[2], p7 = st1[3];

        float lmax = fmaxf(fmaxf(fmaxf(p0, p1), fmaxf(p2, p3)),
                           fmaxf(fmaxf(p4, p5), fmaxf(p6, p7)));
        lmax = fmaxf(lmax, __shfl_xor(lmax, 16));
        lmax = fmaxf(lmax, __shfl_xor(lmax, 32));
        const float mnew = fmaxf(m, lmax);
        const float corr = __expf(m - mnew);
        m = mnew;

        p0 = __expf(p0 - m); p1 = __expf(p1 - m);
        p2 = __expf(p2 - m); p3 = __expf(p3 - m);
        p4 = __expf(p4 - m); p5 = __expf(p5 - m);
        p6 = __expf(p6 - m); p7 = __expf(p7 - m);

        if (kb + 32 > LDIM) {
            if (kb + 4 * g + 0  >= LDIM) p0 = 0.f;
            if (kb + 4 * g + 1  >= LDIM) p1 = 0.f;
            if (kb + 4 * g + 2  >= LDIM) p2 = 0.f;
            if (kb + 4 * g + 3  >= LDIM) p3 = 0.f;
            if (kb + 16 + 4 * g + 0 >= LDIM) p4 = 0.f;
            if (kb + 16 + 4 * g + 1 >= LDIM) p5 = 0.f;
            if (kb + 16 + 4 * g + 2 >= LDIM) p6 = 0.f;
            if (kb + 16 + 4 * g + 3 >= LDIM) p7 = 0.f;
        }

        float ls = ((p0 + p1) + (p2 + p3)) + ((p4 + p5) + (p6 + p7));
        ls += __shfl_xor(ls, 16);
        ls += __shfl_xor(ls, 32);
        s = s * corr + ls;
        o[0] *= corr; o[1] *= corr; o[2] *= corr; o[3] *= corr;

        const unsigned b0 = pack2(p0, p1), b1 = pack2(p2, p3);
        const unsigned b2 = pack2(p4, p5), b3 = pack2(p6, p7);
        const unsigned x0 = __shfl((int)b0, srcA), x1 = __shfl((int)b1, srcA);
        const unsigned x2 = __shfl((int)b0, srcB), x3 = __shfl((int)b1, srcB);
        const unsigned y0 = __shfl((int)b2, srcA), y1 = __shfl((int)b3, srcA);
        const unsigned y2 = __shfl((int)b2, srcB), y3 = __shfl((int)b3, srcB);
        const bool lo = g < 2;
        union { unsigned u[4]; bf16x8 v; } pw;
        pw.u[0] = lo ? x0 : y0;
        pw.u[1] = lo ? x1 : y1;
        pw.u[2] = lo ? x2 : y2;
        pw.u[3] = lo ? x3 : y3;

        o = __builtin_amdgcn_mfma_f32_16x16x32_bf16(vf, pw.v, o, 0, 0, 0);
    }

    const int q = q0 + lq;
    if (q < LDIM) {
        const float inv = 1.f / s;
#pragma unroll
        for (int r = 0; r < 4; ++r)
            Oh[((size_t)(n * 128 + h * 16 + g * 4 + r)) * LDIM + q] = o[r] * inv;
    }
}

// ---------------------------------------------------------------------------
// 5. Output projection (fp32, unchanged).
__global__ __launch_bounds__(256) void out_proj_kernel(
        const float* __restrict__ Oh, const float* __restrict__ ow,
        const float* __restrict__ ob, float* __restrict__ out) {
    const int pt = blockIdx.x, og = blockIdx.y, n = blockIdx.z;
    const int p = pt * 256 + threadIdx.x;
    const bool valid = p < LDIM;
    const int pc = valid ? p : LDIM - 1;
    float acc[16];
#pragma unroll
    for (int k = 0; k < 16; ++k) acc[k] = 0.f;
    const float* ohp = Oh + (size_t)n * 128 * LDIM + pc;
    const int o0 = og * 16;
    for (int i = 0; i < 128; ++i) {
        const float v = ohp[(size_t)i * LDIM];
#pragma unroll
        for (int k = 0; k < 16; ++k)
            acc[k] = fmaf(ow[(o0 + k) * 128 + i], v, acc[k]);
    }
    if (!valid) return;
#pragma unroll
    for (int k = 0; k < 16; ++k)
        out[(size_t)(n * 128 + o0 + k) * LDIM + p] = acc[k] + ob[o0 + k];
}

// ---------------------------------------------------------------------------
extern "C" void kernel_launch(void* const* d_in, const int* in_sizes, int n_in,
                              void* d_out, int out_size, void* d_ws, size_t ws_size,
                              hipStream_t stream) {
    const float* x     = (const float*)d_in[0];
    const float* qkv_w = (const float*)d_in[1];
    const float* qkv_b = (const float*)d_in[2];
    const float* out_w = (const float*)d_in[3];
    const float* out_b = (const float*)d_in[4];
    float* ws = (float*)d_ws;
    ushort_t* xpT = (ushort_t*)(ws + XPT_OFF);
    ushort_t* wT2 = (ushort_t*)(ws + WT_OFF);
    ushort_t* qT  = (ushort_t*)(ws + Q_OFF);
    ushort_t* kT  = (ushort_t*)(ws + K_OFF);
    ushort_t* vTT = (ushort_t*)(ws + V_OFF);
    float*    Oh  = ws + OH_OFF;
    float*    out = (float*)d_out;

    pad_split_x_kernel<<<2048, 256, 0, stream>>>(x, xpT);
    w_split_kernel<<<4320, 256, 0, stream>>>(qkv_w, wT2);
    conv_mfma_kernel<<<dim3(11, 10, NB), 256, 0, stream>>>(xpT, wT2, qkv_b,
                                                           qT, kT, vTT);
    attn_mfma_kernel<<<dim3(43, NB * NHH), 256, 0, stream>>>(qT, kT, vTT, Oh);
    out_proj_kernel<<<dim3(11, 8, NB), 256, 0, stream>>>(Oh, out_w, out_b, out);
}

// Round 4
// 213.482 us; speedup vs baseline: 4.1751x; 1.3362x over previous
//
#include <hip/hip_runtime.h>

typedef short bf16x8 __attribute__((ext_vector_type(8)));
typedef float f32x4 __attribute__((ext_vector_type(4)));
typedef unsigned short ushort_t;

// Problem constants
constexpr int NB   = 2;
constexpr int ICH  = 64;
constexpr int LDIM = 2744;   // 14^3
constexpr int LPAD = 2752;   // multiple of 32
constexpr int NHH  = 8;
constexpr int KCH  = LPAD / 8;   // 344 key-chunks for V layout

// Workspace layout (float offsets)
// xs : [n][kc 16][pos 4096][8us]   kc = (hi?0:8)+ic/8      -> 524288 f
// wt : [t 27][kc 16][oc 640][8us]                          -> 1105920 f
// qs : [nh 16][g 4][p 2752][8us]   g = d/8                 -> 704512 f
// ks : same as qs                                          -> 704512 f
// vs : [nh 16][kc 344][dv 16][8us] kc = key/8              -> 352256 f
// Oh : fp32 [n 2][128][2744]                               -> 702464 f
constexpr size_t XS_OFF = 0;
constexpr size_t WT_OFF = 524288;
constexpr size_t Q_OFF  = WT_OFF + 1105920;
constexpr size_t K_OFF  = Q_OFF + 704512;
constexpr size_t V_OFF  = K_OFF + 704512;
constexpr size_t OH_OFF = V_OFF + 352256;

// fp32 -> bf16 round-to-nearest-even (inputs guaranteed finite)
__device__ __forceinline__ ushort_t bf16_rn(float x) {
    unsigned u = __float_as_uint(x);
    u += 0x7FFFu + ((u >> 16) & 1u);
    return (ushort_t)(u >> 16);
}
__device__ __forceinline__ float bf16_f(ushort_t h) {
    return __uint_as_float((unsigned)h << 16);
}
__device__ __forceinline__ unsigned pack2(float a, float b) {
    return (unsigned)bf16_rn(a) | ((unsigned)bf16_rn(b) << 16);
}

// ---------------------------------------------------------------------------
// 1. Pad + transpose + bf16-split x into chunked layout.
//    Thread idx: pos fastest -> coalesced x reads.
__global__ __launch_bounds__(256) void pad_split_x_kernel(
        const float* __restrict__ x, ushort_t* __restrict__ xs) {
    int idx = blockIdx.x * 256 + threadIdx.x;      // 2*64*4096
    int n  = idx >> 18;
    int ic = (idx >> 12) & 63;
    int pos = idx & 4095;
    int z = pos >> 8, y = (pos >> 4) & 15, xx = pos & 15;
    float v = 0.f;
    if (z >= 1 && z <= 14 && y >= 1 && y <= 14 && xx >= 1 && xx <= 14)
        v = x[(n * 64 + ic) * LDIM + (z - 1) * 196 + (y - 1) * 14 + (xx - 1)];
    ushort_t hi = bf16_rn(v);
    float lo = v - bf16_f(hi);
    xs[((size_t)(n * 16 + (ic >> 3)) * 4096 + pos) * 8 + (ic & 7)] = hi;
    xs[((size_t)(n * 16 + 8 + (ic >> 3)) * 4096 + pos) * 8 + (ic & 7)] = bf16_rn(lo);
}

// ---------------------------------------------------------------------------
// 2. Transpose + bf16-split weights into chunked layout.
__global__ __launch_bounds__(256) void w_split_kernel(
        const float* __restrict__ w, ushort_t* __restrict__ wt) {
    int idx = blockIdx.x * 256 + threadIdx.x;      // 27*640*64
    int t = idx / 40960;
    int r = idx % 40960;
    int oc = r >> 6, ic = r & 63;
    float v = w[(oc * 64 + ic) * 27 + t];
    ushort_t hi = bf16_rn(v);
    float lo = v - bf16_f(hi);
    wt[((size_t)(t * 16 + (ic >> 3)) * 640 + oc) * 8 + (ic & 7)] = hi;
    wt[((size_t)(t * 16 + 8 + (ic >> 3)) * 640 + oc) * 8 + (ic & 7)] = bf16_rn(lo);
}

// ---------------------------------------------------------------------------
// 3. Conv as 27 shifted K=64 MFMA GEMM-accumulates, 3-pass bf16 split.
//    All fragment loads are contiguous 256B segments per 16-lane group.
__global__ __launch_bounds__(256) void conv_mfma_kernel(
        const ushort_t* __restrict__ xs, const ushort_t* __restrict__ wt,
        const float* __restrict__ b, ushort_t* __restrict__ qs,
        ushort_t* __restrict__ ks, ushort_t* __restrict__ vs) {
    const int n = blockIdx.z, ocg = blockIdx.y;
    const int wave = threadIdx.x >> 6, lane = threadIdx.x & 63;
    const int lq = lane & 15, g = lane >> 4;
    const int p0 = blockIdx.x * 256 + wave * 64;
    const int oc0 = ocg * 64;

    int posi[4], pcol[4];
#pragma unroll
    for (int ps = 0; ps < 4; ++ps) {
        int p = p0 + ps * 16 + lq;
        pcol[ps] = p;
        int pc = p < LDIM ? p : LDIM - 1;
        int z = pc / 196, rr = pc % 196, y = rr / 14, xx = rr % 14;
        posi[ps] = z * 256 + y * 16 + xx;
    }

    const bf16x8* XB = (const bf16x8*)xs + (size_t)n * 16 * 4096;
    const bf16x8* WB = (const bf16x8*)wt;

    f32x4 acc[4][4];
#pragma unroll
    for (int os = 0; os < 4; ++os)
#pragma unroll
        for (int ps = 0; ps < 4; ++ps)
            acc[os][ps] = (f32x4){0.f, 0.f, 0.f, 0.f};

    for (int t = 0; t < 27; ++t) {
        const int tz = t / 9, tr = t % 9, ty = tr / 3, tx = tr % 3;
        const int toff = tz * 256 + ty * 16 + tx;

        bf16x8 bh0[4], bh1[4], bl0[4], bl1[4];
#pragma unroll
        for (int ps = 0; ps < 4; ++ps) {
            const int base = posi[ps] + toff;
            bh0[ps] = XB[(size_t)(g) * 4096 + base];
            bh1[ps] = XB[(size_t)(4 + g) * 4096 + base];
            bl0[ps] = XB[(size_t)(8 + g) * 4096 + base];
            bl1[ps] = XB[(size_t)(12 + g) * 4096 + base];
        }
        const bf16x8* Wt = WB + (size_t)t * 16 * 640;
#pragma unroll
        for (int os = 0; os < 4; ++os) {
            const int oc = oc0 + os * 16 + lq;
            const bf16x8 ah0 = Wt[(size_t)(g) * 640 + oc];
            const bf16x8 ah1 = Wt[(size_t)(4 + g) * 640 + oc];
            const bf16x8 al0 = Wt[(size_t)(8 + g) * 640 + oc];
            const bf16x8 al1 = Wt[(size_t)(12 + g) * 640 + oc];
#pragma unroll
            for (int ps = 0; ps < 4; ++ps) {
                f32x4 a = acc[os][ps];
                a = __builtin_amdgcn_mfma_f32_16x16x32_bf16(ah0, bh0[ps], a, 0, 0, 0);
                a = __builtin_amdgcn_mfma_f32_16x16x32_bf16(ah1, bh1[ps], a, 0, 0, 0);
                a = __builtin_amdgcn_mfma_f32_16x16x32_bf16(al0, bh0[ps], a, 0, 0, 0);
                a = __builtin_amdgcn_mfma_f32_16x16x32_bf16(al1, bh1[ps], a, 0, 0, 0);
                a = __builtin_amdgcn_mfma_f32_16x16x32_bf16(ah0, bl0[ps], a, 0, 0, 0);
                a = __builtin_amdgcn_mfma_f32_16x16x32_bf16(ah1, bl1[ps], a, 0, 0, 0);
                acc[os][ps] = a;
            }
        }
    }

    // Epilogue: bias + route to qs/ks/vs (branch block-uniform in ocg).
#pragma unroll
    for (int os = 0; os < 4; ++os) {
#pragma unroll
        for (int ps = 0; ps < 4; ++ps) {
            if (pcol[ps] >= LDIM) continue;
            const int p = pcol[ps];
#pragma unroll
            for (int i = 0; i < 4; ++i) {
                const int oc = oc0 + os * 16 + g * 4 + i;
                const float val = acc[os][ps][i] + b[oc];
                if (oc0 < 256) {          // q, pre-scaled
                    const int h = oc >> 5, d = oc & 31;
                    qs[((size_t)((n * NHH + h) * 4 + (d >> 3)) * LPAD + p) * 8 + (d & 7)] =
                        bf16_rn(val * 0.17677669529663687f);
                } else if (oc0 < 512) {   // k
                    const int c = oc - 256, h = c >> 5, d = c & 31;
                    ks[((size_t)((n * NHH + h) * 4 + (d >> 3)) * LPAD + p) * 8 + (d & 7)] =
                        bf16_rn(val);
                } else {                  // v
                    const int c = oc - 512, h = c >> 4, dv = c & 15;
                    vs[((size_t)((n * NHH + h) * KCH + (p >> 3)) * 16 + dv) * 8 + (p & 7)] =
                        bf16_rn(val);
                }
            }
        }
    }
}

// ---------------------------------------------------------------------------
// 4. Flash attention, bf16 MFMA 16x16x32, chunked coalesced layouts.
__global__ __launch_bounds__(256) void attn_mfma_kernel(
        const ushort_t* __restrict__ qs, const ushort_t* __restrict__ ks,
        const ushort_t* __restrict__ vs, float* __restrict__ Oh) {
    const int nh = blockIdx.y, n = nh >> 3, h = nh & 7;
    const int wave = threadIdx.x >> 6, lane = threadIdx.x & 63;
    const int lq = lane & 15, g = lane >> 4;
    const int q0 = blockIdx.x * 64 + wave * 16;

    const bf16x8* QS = (const bf16x8*)qs;
    const bf16x8 qf = QS[((size_t)nh * 4 + g) * LPAD + q0 + lq];
    const bf16x8* KS = (const bf16x8*)ks + (size_t)nh * 4 * LPAD;
    const bf16x8* VS = (const bf16x8*)vs + (size_t)nh * KCH * 16 + lq;

    f32x4 o = {0.f, 0.f, 0.f, 0.f};
    float m = -1e30f, s = 0.f;
    const int srcA = lq + 32 * (g & 1);
    const int srcB = srcA + 16;

    for (int kb = 0; kb < LDIM; kb += 32) {
        const bf16x8 kA = KS[(size_t)g * LPAD + kb + lq];
        const bf16x8 kB = KS[(size_t)g * LPAD + kb + 16 + lq];
        const bf16x8 vf = VS[(size_t)((kb >> 3) + g) * 16];

        const f32x4 z = {0.f, 0.f, 0.f, 0.f};
        f32x4 st0 = __builtin_amdgcn_mfma_f32_16x16x32_bf16(kA, qf, z, 0, 0, 0);
        f32x4 st1 = __builtin_amdgcn_mfma_f32_16x16x32_bf16(kB, qf, z, 0, 0, 0);

        float p0 = st0[0], p1 = st0[1], p2 = st0[2], p3 = st0[3];
        float p4 = st1[0], p5 = st1[1], p6 = st1[2], p7 = st1[3];

        float lmax = fmaxf(fmaxf(fmaxf(p0, p1), fmaxf(p2, p3)),
                           fmaxf(fmaxf(p4, p5), fmaxf(p6, p7)));
        lmax = fmaxf(lmax, __shfl_xor(lmax, 16));
        lmax = fmaxf(lmax, __shfl_xor(lmax, 32));
        const float mnew = fmaxf(m, lmax);
        const float corr = __expf(m - mnew);
        m = mnew;

        p0 = __expf(p0 - m); p1 = __expf(p1 - m);
        p2 = __expf(p2 - m); p3 = __expf(p3 - m);
        p4 = __expf(p4 - m); p5 = __expf(p5 - m);
        p6 = __expf(p6 - m); p7 = __expf(p7 - m);

        if (kb + 32 > LDIM) {
            if (kb + 4 * g + 0  >= LDIM) p0 = 0.f;
            if (kb + 4 * g + 1  >= LDIM) p1 = 0.f;
            if (kb + 4 * g + 2  >= LDIM) p2 = 0.f;
            if (kb + 4 * g + 3  >= LDIM) p3 = 0.f;
            if (kb + 16 + 4 * g + 0 >= LDIM) p4 = 0.f;
            if (kb + 16 + 4 * g + 1 >= LDIM) p5 = 0.f;
            if (kb + 16 + 4 * g + 2 >= LDIM) p6 = 0.f;
            if (kb + 16 + 4 * g + 3 >= LDIM) p7 = 0.f;
        }

        float ls = ((p0 + p1) + (p2 + p3)) + ((p4 + p5) + (p6 + p7));
        ls += __shfl_xor(ls, 16);
        ls += __shfl_xor(ls, 32);
        s = s * corr + ls;
        o[0] *= corr; o[1] *= corr; o[2] *= corr; o[3] *= corr;

        const unsigned b0 = pack2(p0, p1), b1 = pack2(p2, p3);
        const unsigned b2 = pack2(p4, p5), b3 = pack2(p6, p7);
        const unsigned x0 = __shfl((int)b0, srcA), x1 = __shfl((int)b1, srcA);
        const unsigned x2 = __shfl((int)b0, srcB), x3 = __shfl((int)b1, srcB);
        const unsigned y0 = __shfl((int)b2, srcA), y1 = __shfl((int)b3, srcA);
        const unsigned y2 = __shfl((int)b2, srcB), y3 = __shfl((int)b3, srcB);
        const bool lo = g < 2;
        union { unsigned u[4]; bf16x8 v; } pw;
        pw.u[0] = lo ? x0 : y0;
        pw.u[1] = lo ? x1 : y1;
        pw.u[2] = lo ? x2 : y2;
        pw.u[3] = lo ? x3 : y3;

        o = __builtin_amdgcn_mfma_f32_16x16x32_bf16(vf, pw.v, o, 0, 0, 0);
    }

    const int q = q0 + lq;
    if (q < LDIM) {
        const float inv = 1.f / s;
#pragma unroll
        for (int r = 0; r < 4; ++r)
            Oh[((size_t)(n * 128 + h * 16 + g * 4 + r)) * LDIM + q] = o[r] * inv;
    }
}

// ---------------------------------------------------------------------------
// 5. Output projection (fp32), 8 outputs/thread for 2x grid.
__global__ __launch_bounds__(256) void out_proj_kernel(
        const float* __restrict__ Oh, const float* __restrict__ ow,
        const float* __restrict__ ob, float* __restrict__ out) {
    const int pt = blockIdx.x, og = blockIdx.y, n = blockIdx.z;
    const int p = pt * 256 + threadIdx.x;
    const bool valid = p < LDIM;
    const int pc = valid ? p : LDIM - 1;
    float acc[8];
#pragma unroll
    for (int k = 0; k < 8; ++k) acc[k] = 0.f;
    const float* ohp = Oh + (size_t)n * 128 * LDIM + pc;
    const int o0 = og * 8;
    for (int i = 0; i < 128; i += 4) {
        float v0 = ohp[(size_t)(i + 0) * LDIM];
        float v1 = ohp[(size_t)(i + 1) * LDIM];
        float v2 = ohp[(size_t)(i + 2) * LDIM];
        float v3 = ohp[(size_t)(i + 3) * LDIM];
#pragma unroll
        for (int k = 0; k < 8; ++k) {
            acc[k] = fmaf(ow[(o0 + k) * 128 + i + 0], v0, acc[k]);
            acc[k] = fmaf(ow[(o0 + k) * 128 + i + 1], v1, acc[k]);
            acc[k] = fmaf(ow[(o0 + k) * 128 + i + 2], v2, acc[k]);
            acc[k] = fmaf(ow[(o0 + k) * 128 + i + 3], v3, acc[k]);
        }
    }
    if (!valid) return;
#pragma unroll
    for (int k = 0; k < 8; ++k)
        out[(size_t)(n * 128 + o0 + k) * LDIM + p] = acc[k] + ob[o0 + k];
}

// ---------------------------------------------------------------------------
extern "C" void kernel_launch(void* const* d_in, const int* in_sizes, int n_in,
                              void* d_out, int out_size, void* d_ws, size_t ws_size,
                              hipStream_t stream) {
    const float* x     = (const float*)d_in[0];
    const float* qkv_w = (const float*)d_in[1];
    const float* qkv_b = (const float*)d_in[2];
    const float* out_w = (const float*)d_in[3];
    const float* out_b = (const float*)d_in[4];
    float* ws = (float*)d_ws;
    ushort_t* xs = (ushort_t*)(ws + XS_OFF);
    ushort_t* wt = (ushort_t*)(ws + WT_OFF);
    ushort_t* qsp = (ushort_t*)(ws + Q_OFF);
    ushort_t* ksp = (ushort_t*)(ws + K_OFF);
    ushort_t* vsp = (ushort_t*)(ws + V_OFF);
    float*    Oh  = ws + OH_OFF;
    float*    out = (float*)d_out;

    pad_split_x_kernel<<<2048, 256, 0, stream>>>(x, xs);
    w_split_kernel<<<4320, 256, 0, stream>>>(qkv_w, wt);
    conv_mfma_kernel<<<dim3(11, 10, NB), 256, 0, stream>>>(xs, wt, qkv_b,
                                                           qsp, ksp, vsp);
    attn_mfma_kernel<<<dim3(43, NB * NHH), 256, 0, stream>>>(qsp, ksp, vsp, Oh);
    out_proj_kernel<<<dim3(11, 16, NB), 256, 0, stream>>>(Oh, out_w, out_b, out);
}

// Round 5
// 175.866 us; speedup vs baseline: 5.0681x; 1.2139x over previous
//
#include <hip/hip_runtime.h>

typedef short bf16x8 __attribute__((ext_vector_type(8)));
typedef float f32x4 __attribute__((ext_vector_type(4)));
typedef unsigned short ushort_t;

// Problem constants
constexpr int NB   = 2;
constexpr int ICH  = 64;
constexpr int LDIM = 2744;   // 14^3
constexpr int LPAD = 2752;   // multiple of 32
constexpr int NHH  = 8;
constexpr int KCH  = LPAD / 8;   // 344 key-chunks for V layout

// q scale: 1/sqrt(32) * log2(e)  (exp2-domain softmax)
#define QSCL (0.17677669529663687f * 1.4426950408889634f)

// Workspace layout (float offsets)
constexpr size_t XS_OFF = 0;                      // 524288 f
constexpr size_t WT_OFF = 524288;                 // 1105920 f
constexpr size_t Q_OFF  = WT_OFF + 1105920;       // 704512 f
constexpr size_t K_OFF  = Q_OFF + 704512;         // 704512 f
constexpr size_t V_OFF  = K_OFF + 704512;         // 352256 f
constexpr size_t OH_OFF = V_OFF + 352256;         // 702464 f

__device__ __forceinline__ ushort_t bf16_rn(float x) {
    unsigned u = __float_as_uint(x);
    u += 0x7FFFu + ((u >> 16) & 1u);
    return (ushort_t)(u >> 16);
}
__device__ __forceinline__ float bf16_f(ushort_t h) {
    return __uint_as_float((unsigned)h << 16);
}
__device__ __forceinline__ float exp2_hw(float x) {
    float r;
    asm("v_exp_f32 %0, %1" : "=v"(r) : "v"(x));
    return r;
}
__device__ __forceinline__ unsigned cvt_pk_bf16(float lo, float hi) {
    unsigned r;
    asm("v_cvt_pk_bf16_f32 %0, %1, %2" : "=v"(r) : "v"(lo), "v"(hi));
    return r;
}

// ---------------------------------------------------------------------------
// 1. Pad + transpose + bf16-split x into chunked layout.
__global__ __launch_bounds__(256) void pad_split_x_kernel(
        const float* __restrict__ x, ushort_t* __restrict__ xs) {
    int idx = blockIdx.x * 256 + threadIdx.x;      // 2*64*4096
    int n  = idx >> 18;
    int ic = (idx >> 12) & 63;
    int pos = idx & 4095;
    int z = pos >> 8, y = (pos >> 4) & 15, xx = pos & 15;
    float v = 0.f;
    if (z >= 1 && z <= 14 && y >= 1 && y <= 14 && xx >= 1 && xx <= 14)
        v = x[(n * 64 + ic) * LDIM + (z - 1) * 196 + (y - 1) * 14 + (xx - 1)];
    ushort_t hi = bf16_rn(v);
    float lo = v - bf16_f(hi);
    xs[((size_t)(n * 16 + (ic >> 3)) * 4096 + pos) * 8 + (ic & 7)] = hi;
    xs[((size_t)(n * 16 + 8 + (ic >> 3)) * 4096 + pos) * 8 + (ic & 7)] = bf16_rn(lo);
}

// ---------------------------------------------------------------------------
// 2. Transpose + bf16-split weights into chunked layout.
__global__ __launch_bounds__(256) void w_split_kernel(
        const float* __restrict__ w, ushort_t* __restrict__ wt) {
    int idx = blockIdx.x * 256 + threadIdx.x;      // 27*640*64
    int t = idx / 40960;
    int r = idx % 40960;
    int oc = r >> 6, ic = r & 63;
    float v = w[(oc * 64 + ic) * 27 + t];
    ushort_t hi = bf16_rn(v);
    float lo = v - bf16_f(hi);
    wt[((size_t)(t * 16 + (ic >> 3)) * 640 + oc) * 8 + (ic & 7)] = hi;
    wt[((size_t)(t * 16 + 8 + (ic >> 3)) * 640 + oc) * 8 + (ic & 7)] = bf16_rn(lo);
}

// ---------------------------------------------------------------------------
// 3. Conv as 27 shifted K=64 MFMA GEMM-accumulates, 3-pass bf16 split.
//    Wave tile 64oc x 32p (2x waves vs r4); A hoisted per tap; B prefetched
//    one tap ahead.
__global__ __launch_bounds__(256, 2) void conv_mfma_kernel(
        const ushort_t* __restrict__ xs, const ushort_t* __restrict__ wt,
        const float* __restrict__ b, ushort_t* __restrict__ qs,
        ushort_t* __restrict__ ks, ushort_t* __restrict__ vs) {
    const int n = blockIdx.z, ocg = blockIdx.y;
    const int wave = threadIdx.x >> 6, lane = threadIdx.x & 63;
    const int lq = lane & 15, g = lane >> 4;
    const int p0 = blockIdx.x * 128 + wave * 32;
    const int oc0 = ocg * 64;

    int posi[2], pcol[2];
#pragma unroll
    for (int ps = 0; ps < 2; ++ps) {
        int p = p0 + ps * 16 + lq;
        pcol[ps] = p;
        int pc = p < LDIM ? p : LDIM - 1;
        int z = pc / 196, rr = pc % 196, y = rr / 14, xx = rr % 14;
        posi[ps] = z * 256 + y * 16 + xx;
    }

    const bf16x8* XB = (const bf16x8*)xs + (size_t)n * 16 * 4096;
    const bf16x8* WB = (const bf16x8*)wt;

    f32x4 acc[4][2];
#pragma unroll
    for (int os = 0; os < 4; ++os)
#pragma unroll
        for (int ps = 0; ps < 2; ++ps)
            acc[os][ps] = (f32x4){0.f, 0.f, 0.f, 0.f};

    // B fragments (current + next tap)
    bf16x8 bh0[2], bh1[2], bl0[2], bl1[2];
    bf16x8 nh0[2], nh1[2], nl0[2], nl1[2];

#pragma unroll
    for (int ps = 0; ps < 2; ++ps) {                  // tap 0 (toff = 273)
        const int base = posi[ps] + 273;               // 1*256+1*16+1... t=0 -> tz=0,ty=0,tx=0 -> toff=0
        const int b0 = posi[ps];                       // correct toff for t=0 is 0
        bh0[ps] = XB[(size_t)(g) * 4096 + b0];
        bh1[ps] = XB[(size_t)(4 + g) * 4096 + b0];
        bl0[ps] = XB[(size_t)(8 + g) * 4096 + b0];
        bl1[ps] = XB[(size_t)(12 + g) * 4096 + b0];
        (void)base;
    }

    for (int t = 0; t < 27; ++t) {
        // A fragments for this tap (all 4 os), issued first
        const bf16x8* Wt = WB + (size_t)t * 16 * 640;
        bf16x8 A[4][4];
#pragma unroll
        for (int os = 0; os < 4; ++os) {
            const int oc = oc0 + os * 16 + lq;
            A[os][0] = Wt[(size_t)(g) * 640 + oc];
            A[os][1] = Wt[(size_t)(4 + g) * 640 + oc];
            A[os][2] = Wt[(size_t)(8 + g) * 640 + oc];
            A[os][3] = Wt[(size_t)(12 + g) * 640 + oc];
        }
        // prefetch next tap's B
        if (t < 26) {
            const int tn = t + 1;
            const int tz = tn / 9, tr = tn % 9, ty = tr / 3, tx = tr % 3;
            const int toff = tz * 256 + ty * 16 + tx;
#pragma unroll
            for (int ps = 0; ps < 2; ++ps) {
                const int base = posi[ps] + toff;
                nh0[ps] = XB[(size_t)(g) * 4096 + base];
                nh1[ps] = XB[(size_t)(4 + g) * 4096 + base];
                nl0[ps] = XB[(size_t)(8 + g) * 4096 + base];
                nl1[ps] = XB[(size_t)(12 + g) * 4096 + base];
            }
        }
#pragma unroll
        for (int os = 0; os < 4; ++os) {
#pragma unroll
            for (int ps = 0; ps < 2; ++ps) {
                f32x4 a = acc[os][ps];
                a = __builtin_amdgcn_mfma_f32_16x16x32_bf16(A[os][0], bh0[ps], a, 0, 0, 0);
                a = __builtin_amdgcn_mfma_f32_16x16x32_bf16(A[os][1], bh1[ps], a, 0, 0, 0);
                a = __builtin_amdgcn_mfma_f32_16x16x32_bf16(A[os][2], bh0[ps], a, 0, 0, 0);
                a = __builtin_amdgcn_mfma_f32_16x16x32_bf16(A[os][3], bh1[ps], a, 0, 0, 0);
                a = __builtin_amdgcn_mfma_f32_16x16x32_bf16(A[os][0], bl0[ps], a, 0, 0, 0);
                a = __builtin_amdgcn_mfma_f32_16x16x32_bf16(A[os][1], bl1[ps], a, 0, 0, 0);
                acc[os][ps] = a;
            }
        }
        if (t < 26) {
#pragma unroll
            for (int ps = 0; ps < 2; ++ps) {
                bh0[ps] = nh0[ps]; bh1[ps] = nh1[ps];
                bl0[ps] = nl0[ps]; bl1[ps] = nl1[ps];
            }
        }
    }

    // Epilogue: bias + route to qs/ks/vs (branch block-uniform in ocg).
#pragma unroll
    for (int os = 0; os < 4; ++os) {
#pragma unroll
        for (int ps = 0; ps < 2; ++ps) {
            if (pcol[ps] >= LDIM) continue;
            const int p = pcol[ps];
#pragma unroll
            for (int i = 0; i < 4; ++i) {
                const int oc = oc0 + os * 16 + g * 4 + i;
                const float val = acc[os][ps][i] + b[oc];
                if (oc0 < 256) {          // q, pre-scaled into exp2 domain
                    const int h = oc >> 5, d = oc & 31;
                    qs[((size_t)((n * NHH + h) * 4 + (d >> 3)) * LPAD + p) * 8 + (d & 7)] =
                        bf16_rn(val * QSCL);
                } else if (oc0 < 512) {   // k
                    const int c = oc - 256, h = c >> 5, d = c & 31;
                    ks[((size_t)((n * NHH + h) * 4 + (d >> 3)) * LPAD + p) * 8 + (d & 7)] =
                        bf16_rn(val);
                } else {                  // v
                    const int c = oc - 512, h = c >> 4, dv = c & 15;
                    vs[((size_t)((n * NHH + h) * KCH + (p >> 3)) * 16 + dv) * 8 + (p & 7)] =
                        bf16_rn(val);
                }
            }
        }
    }
}

// ---------------------------------------------------------------------------
// 4. Flash attention, bf16 MFMA, no-max exp2 softmax (logits bounded),
//    hw cvt_pk packing, next-tile K/V register prefetch.
__global__ __launch_bounds__(256) void attn_mfma_kernel(
        const ushort_t* __restrict__ qs, const ushort_t* __restrict__ ks,
        const ushort_t* __restrict__ vs, float* __restrict__ Oh) {
    const int nh = blockIdx.y, n = nh >> 3, h = nh & 7;
    const int wave = threadIdx.x >> 6, lane = threadIdx.x & 63;
    const int lq = lane & 15, g = lane >> 4;
    const int q0 = blockIdx.x * 64 + wave * 16;

    const bf16x8* QS = (const bf16x8*)qs;
    const bf16x8 qf = QS[((size_t)nh * 4 + g) * LPAD + q0 + lq];
    const bf16x8* KS = (const bf16x8*)ks + (size_t)nh * 4 * LPAD + (size_t)g * LPAD;
    const bf16x8* VS = (const bf16x8*)vs + (size_t)nh * KCH * 16 + lq;

    f32x4 o = {0.f, 0.f, 0.f, 0.f};
    float s = 0.f;
    const int srcA = lq + 32 * (g & 1);
    const int srcB = srcA + 16;

    bf16x8 kA = KS[lq];
    bf16x8 kB = KS[16 + lq];
    bf16x8 vf = VS[(size_t)g * 16];

    for (int kb = 0; kb < LDIM; kb += 32) {
        const int nb = (kb + 32 < LDIM) ? kb + 32 : kb;   // prefetch (clamped)
        bf16x8 kAn = KS[nb + lq];
        bf16x8 kBn = KS[nb + 16 + lq];
        bf16x8 vfn = VS[(size_t)((nb >> 3) + g) * 16];

        const f32x4 z = {0.f, 0.f, 0.f, 0.f};
        f32x4 st0 = __builtin_amdgcn_mfma_f32_16x16x32_bf16(kA, qf, z, 0, 0, 0);
        f32x4 st1 = __builtin_amdgcn_mfma_f32_16x16x32_bf16(kB, qf, z, 0, 0, 0);

        float p0 = exp2_hw(st0[0]), p1 = exp2_hw(st0[1]);
        float p2 = exp2_hw(st0[2]), p3 = exp2_hw(st0[3]);
        float p4 = exp2_hw(st1[0]), p5 = exp2_hw(st1[1]);
        float p6 = exp2_hw(st1[2]), p7 = exp2_hw(st1[3]);

        if (kb + 32 > LDIM) {                 // mask tail keys (>= 2744)
            if (kb + 4 * g + 0  >= LDIM) p0 = 0.f;
            if (kb + 4 * g + 1  >= LDIM) p1 = 0.f;
            if (kb + 4 * g + 2  >= LDIM) p2 = 0.f;
            if (kb + 4 * g + 3  >= LDIM) p3 = 0.f;
            if (kb + 16 + 4 * g + 0 >= LDIM) p4 = 0.f;
            if (kb + 16 + 4 * g + 1 >= LDIM) p5 = 0.f;
            if (kb + 16 + 4 * g + 2 >= LDIM) p6 = 0.f;
            if (kb + 16 + 4 * g + 3 >= LDIM) p7 = 0.f;
        }

        s += ((p0 + p1) + (p2 + p3)) + ((p4 + p5) + (p6 + p7));

        const unsigned b0 = cvt_pk_bf16(p0, p1), b1 = cvt_pk_bf16(p2, p3);
        const unsigned b2 = cvt_pk_bf16(p4, p5), b3 = cvt_pk_bf16(p6, p7);
        const unsigned x0 = __shfl((int)b0, srcA), x1 = __shfl((int)b1, srcA);
        const unsigned x2 = __shfl((int)b0, srcB), x3 = __shfl((int)b1, srcB);
        const unsigned y0 = __shfl((int)b2, srcA), y1 = __shfl((int)b3, srcA);
        const unsigned y2 = __shfl((int)b2, srcB), y3 = __shfl((int)b3, srcB);
        const bool lo = g < 2;
        union { unsigned u[4]; bf16x8 v; } pw;
        pw.u[0] = lo ? x0 : y0;
        pw.u[1] = lo ? x1 : y1;
        pw.u[2] = lo ? x2 : y2;
        pw.u[3] = lo ? x3 : y3;

        o = __builtin_amdgcn_mfma_f32_16x16x32_bf16(vf, pw.v, o, 0, 0, 0);

        kA = kAn; kB = kBn; vf = vfn;
    }

    s += __shfl_xor(s, 16);
    s += __shfl_xor(s, 32);

    const int q = q0 + lq;
    if (q < LDIM) {
        const float inv = 1.f / s;
#pragma unroll
        for (int r = 0; r < 4; ++r)
            Oh[((size_t)(n * 128 + h * 16 + g * 4 + r)) * LDIM + q] = o[r] * inv;
    }
}

// ---------------------------------------------------------------------------
// 5. Output projection (fp32), 8 outputs/thread.
__global__ __launch_bounds__(256) void out_proj_kernel(
        const float* __restrict__ Oh, const float* __restrict__ ow,
        const float* __restrict__ ob, float* __restrict__ out) {
    const int pt = blockIdx.x, og = blockIdx.y, n = blockIdx.z;
    const int p = pt * 256 + threadIdx.x;
    const bool valid = p < LDIM;
    const int pc = valid ? p : LDIM - 1;
    float acc[8];
#pragma unroll
    for (int k = 0; k < 8; ++k) acc[k] = 0.f;
    const float* ohp = Oh + (size_t)n * 128 * LDIM + pc;
    const int o0 = og * 8;
    for (int i = 0; i < 128; i += 4) {
        float v0 = ohp[(size_t)(i + 0) * LDIM];
        float v1 = ohp[(size_t)(i + 1) * LDIM];
        float v2 = ohp[(size_t)(i + 2) * LDIM];
        float v3 = ohp[(size_t)(i + 3) * LDIM];
#pragma unroll
        for (int k = 0; k < 8; ++k) {
            acc[k] = fmaf(ow[(o0 + k) * 128 + i + 0], v0, acc[k]);
            acc[k] = fmaf(ow[(o0 + k) * 128 + i + 1], v1, acc[k]);
            acc[k] = fmaf(ow[(o0 + k) * 128 + i + 2], v2, acc[k]);
            acc[k] = fmaf(ow[(o0 + k) * 128 + i + 3], v3, acc[k]);
        }
    }
    if (!valid) return;
#pragma unroll
    for (int k = 0; k < 8; ++k)
        out[(size_t)(n * 128 + o0 + k) * LDIM + p] = acc[k] + ob[o0 + k];
}

// ---------------------------------------------------------------------------
extern "C" void kernel_launch(void* const* d_in, const int* in_sizes, int n_in,
                              void* d_out, int out_size, void* d_ws, size_t ws_size,
                              hipStream_t stream) {
    const float* x     = (const float*)d_in[0];
    const float* qkv_w = (const float*)d_in[1];
    const float* qkv_b = (const float*)d_in[2];
    const float* out_w = (const float*)d_in[3];
    const float* out_b = (const float*)d_in[4];
    float* ws = (float*)d_ws;
    ushort_t* xsp = (ushort_t*)(ws + XS_OFF);
    ushort_t* wtp = (ushort_t*)(ws + WT_OFF);
    ushort_t* qsp = (ushort_t*)(ws + Q_OFF);
    ushort_t* ksp = (ushort_t*)(ws + K_OFF);
    ushort_t* vsp = (ushort_t*)(ws + V_OFF);
    float*    Oh  = ws + OH_OFF;
    float*    out = (float*)d_out;

    pad_split_x_kernel<<<2048, 256, 0, stream>>>(x, xsp);
    w_split_kernel<<<4320, 256, 0, stream>>>(qkv_w, wtp);
    conv_mfma_kernel<<<dim3(22, 10, NB), 256, 0, stream>>>(xsp, wtp, qkv_b,
                                                           qsp, ksp, vsp);
    attn_mfma_kernel<<<dim3(43, NB * NHH), 256, 0, stream>>>(qsp, ksp, vsp, Oh);
    out_proj_kernel<<<dim3(11, 16, NB), 256, 0, stream>>>(Oh, out_w, out_b, out);
}